// Round 22
// baseline (298.874 us; speedup 1.0000x reference)
//
#include <hip/hip_runtime.h>
#include <hip/hip_bf16.h>
#include <math.h>

#define N_NODES 10000
#define N_EDGES 64000
#define H 128
#define L 8
#define NL (N_NODES * L)

typedef __attribute__((ext_vector_type(4))) float f32x4;
typedef __attribute__((ext_vector_type(8))) __bf16 bf16x8;
typedef __attribute__((ext_vector_type(4))) __bf16 bf16x4;

__device__ __forceinline__ float silu_f(float x) { return x / (1.f + __expf(-x)); }

// ---------------- prep2: wconv+bias | vecw | ln | fgather | dgather (one launch) ----------
// bid ranges: [0,256) wconv | 256 bqkv | 257 bfm | [258,5258) vecw | [5258,7758) ln
//             | [7758,15758) fgather | [15758,17758) dgather
__global__ __launch_bounds__(256) void prep2_kernel(
    const float* __restrict__ Wvec, const float* __restrict__ Wq, const float* __restrict__ Wk,
    const float* __restrict__ Wv, const float* __restrict__ Wdk, const float* __restrict__ Wdv,
    const float* __restrict__ Ws, const float* __restrict__ Wtrg, const float* __restrict__ Wsrc,
    const float* __restrict__ Wf, const float* __restrict__ Wo,
    const float* __restrict__ bq, const float* __restrict__ bk, const float* __restrict__ bv,
    const float* __restrict__ bdk, const float* __restrict__ bdv, const float* __restrict__ bf,
    __bf16* __restrict__ Wt, float* __restrict__ bqkv, float* __restrict__ bfm,
    const float* __restrict__ x, const float* __restrict__ g, const float* __restrict__ b,
    __bf16* __restrict__ xln, const float* __restrict__ vec, const float* __restrict__ w,
    __bf16* __restrict__ vecw, __bf16* __restrict__ vecwT,
    const float* __restrict__ fin, const float* __restrict__ d_ij,
    const float* __restrict__ r_ij, const int* __restrict__ elist,
    __bf16* __restrict__ fout, float* __restrict__ d2, float* __restrict__ r2) {
  __shared__ float tile[32][33];
  int bid = blockIdx.x;
  int t = threadIdx.x;
  if (bid < 256) {
    int ct = bid >> 2, kt = bid & 3;
    int gc0 = ct * 32;
    const float* W; int ldw, sc0;
    if      (gc0 < 384)  { W = Wvec; ldw = 384; sc0 = gc0; }
    else if (gc0 < 512)  { W = Wtrg; ldw = 128; sc0 = gc0 - 384; }
    else if (gc0 < 640)  { W = Wsrc; ldw = 128; sc0 = gc0 - 512; }
    else if (gc0 < 768)  { W = Wq;   ldw = 128; sc0 = gc0 - 640; }
    else if (gc0 < 896)  { W = Wk;   ldw = 128; sc0 = gc0 - 768; }
    else if (gc0 < 1024) { W = Wv;   ldw = 128; sc0 = gc0 - 896; }
    else if (gc0 < 1152) { W = Wdk;  ldw = 128; sc0 = gc0 - 1024; }
    else if (gc0 < 1280) { W = Wdv;  ldw = 128; sc0 = gc0 - 1152; }
    else if (gc0 < 1408) { W = Wf;   ldw = 128; sc0 = gc0 - 1280; }
    else if (gc0 < 1664) { W = Ws;   ldw = 256; sc0 = gc0 - 1408; }
    else                 { W = Wo;   ldw = 384; sc0 = gc0 - 1664; }
    int tx = t & 31, ty = t >> 5;
#pragma unroll
    for (int i = 0; i < 4; ++i)
      tile[ty + i * 8][tx] = W[(size_t)(kt * 32 + ty + i * 8) * ldw + sc0 + tx];
    __syncthreads();
#pragma unroll
    for (int i = 0; i < 4; ++i)
      Wt[(size_t)(gc0 + ty + i * 8) * 128 + kt * 32 + tx] = (__bf16)tile[tx][ty + i * 8];
  } else if (bid == 256) {
    if (t < 128) { bqkv[t] = bq[t]; bqkv[128 + t] = bk[t]; bqkv[256 + t] = bv[t]; }
  } else if (bid == 257) {
    if (t < 128) { bfm[t] = bdk[t]; bfm[128 + t] = bdv[t]; bfm[256 + t] = bf[t]; }
  } else if (bid < 258 + 5000) {
    int n = (bid - 258) * 2 + (t >> 7);
    int h = t & 127;
    float wl = w[h];
    const float* base = vec + (size_t)n * 1024 + h;
    __bf16* orow = vecw + (size_t)n * 1024 + h;
    bf16x8 pack;
#pragma unroll
    for (int l = 0; l < 8; ++l) {
      __bf16 bv = (__bf16)(base[l * 128] * wl);
      orow[l * 128] = bv;
      pack[l] = bv;
    }
    *(bf16x8*)(vecwT + (size_t)n * 1024 + h * 8) = pack;
  } else if (bid < 258 + 5000 + 2500) {
    int wave = t >> 6;
    int lane = t & 63;
    int n = (bid - 258 - 5000) * 4 + wave;
    if (n >= N_NODES) return;
    const float* xr = x + (size_t)n * H;
    float a0 = xr[lane], a1 = xr[lane + 64];
    float s = a0 + a1;
#pragma unroll
    for (int off = 32; off >= 1; off >>= 1) s += __shfl_xor(s, off, 64);
    float mu = s * (1.f / H);
    float d0 = a0 - mu, d1 = a1 - mu;
    float v = d0 * d0 + d1 * d1;
#pragma unroll
    for (int off = 32; off >= 1; off >>= 1) v += __shfl_xor(v, off, 64);
    float rstd = rsqrtf(v * (1.f / H) + 1e-5f);
    __bf16* orow = xln + (size_t)n * H;
    orow[lane] = (__bf16)(d0 * rstd * g[lane] + b[lane]);
    orow[lane + 64] = (__bf16)(d1 * rstd * g[lane + 64] + b[lane + 64]);
  } else if (bid < 258 + 5000 + 2500 + 8000) {
    int p = (bid - 7758) * 8 + (t >> 5);
    int c = (t & 31) * 4;
    int e = elist[p];
    f32x4 a = *(const f32x4*)(fin + (size_t)e * 128 + c);
    bf16x4 h;
    h[0] = (__bf16)a[0]; h[1] = (__bf16)a[1]; h[2] = (__bf16)a[2]; h[3] = (__bf16)a[3];
    *(bf16x4*)(fout + (size_t)p * 128 + c) = h;
  } else {
    int idx = (bid - 15758) * 256 + t;  // over E*8
    int p = idx >> 3, j = idx & 7;
    int e = elist[p];
    d2[idx] = d_ij[(size_t)e * 8 + j];
    if (j == 0) r2[p] = r_ij[e];
  }
}

// ---------------- vdot GEMM: dedicated kernel, no spill ----------------
__global__ __launch_bounds__(256, 2) void vdot_gemm(const __bf16* __restrict__ A,
                                                    const __bf16* __restrict__ Bt,
                                                    float* __restrict__ vdot) {
  __shared__ __bf16 As[128 * 128];
  const int tid = threadIdx.x;
  const int lane = tid & 63;
  const int wave = tid >> 6;
  const int wm = wave >> 1, wn = wave & 1;
  const int row0 = blockIdx.x * 128;

#pragma unroll
  for (int i = 0; i < 8; ++i) {
    int c = tid + i * 256;
    int row = c >> 4, k8 = c & 15;
    int k8s = k8 ^ (row & 7);
    const __bf16* src = A + (size_t)(row0 + row) * 128 + k8s * 8;
    __builtin_amdgcn_global_load_lds((const __attribute__((address_space(1))) void*)src,
                                     (__attribute__((address_space(3))) void*)(As + c * 8),
                                     16, 0, 0);
  }
  __syncthreads();

  f32x4 pacc[4][4], acc[4][4];
#pragma unroll
  for (int mi = 0; mi < 4; ++mi)
#pragma unroll
    for (int ni = 0; ni < 4; ++ni) {
      pacc[mi][ni] = f32x4{0.f, 0.f, 0.f, 0.f};
      acc[mi][ni] = f32x4{0.f, 0.f, 0.f, 0.f};
    }
#pragma unroll
  for (int ct = 0; ct < 2; ++ct) {
    const __bf16* Bbase =
        Bt + ((size_t)(ct * 128 + wn * 64 + (lane & 15)) << 7) + ((lane >> 4) << 3);
#pragma unroll
    for (int ks = 0; ks < 4; ++ks) {
      bf16x8 b[4];
#pragma unroll
      for (int ni = 0; ni < 4; ++ni) b[ni] = *(const bf16x8*)(Bbase + (ni << 11) + (ks << 5));
      bf16x8 a[4];
#pragma unroll
      for (int mi = 0; mi < 4; ++mi) {
        int row = wm * 64 + mi * 16 + (lane & 15);
        int byte = (row * 256 + ks * 64 + ((lane >> 4) << 4)) ^ ((row & 7) << 4);
        a[mi] = *(const bf16x8*)((const char*)As + byte);
      }
      if (ct == 0) {
#pragma unroll
        for (int mi = 0; mi < 4; ++mi)
#pragma unroll
          for (int ni = 0; ni < 4; ++ni)
            pacc[mi][ni] =
                __builtin_amdgcn_mfma_f32_16x16x32_bf16(a[mi], b[ni], pacc[mi][ni], 0, 0, 0);
      } else {
#pragma unroll
        for (int mi = 0; mi < 4; ++mi)
#pragma unroll
          for (int ni = 0; ni < 4; ++ni)
            acc[mi][ni] =
                __builtin_amdgcn_mfma_f32_16x16x32_bf16(a[mi], b[ni], acc[mi][ni], 0, 0, 0);
      }
    }
  }
#pragma unroll
  for (int mi = 0; mi < 4; ++mi) {
#pragma unroll
    for (int ni = 0; ni < 4; ++ni) {
      float sr = pacc[mi][ni][0] * acc[mi][ni][0] + pacc[mi][ni][1] * acc[mi][ni][1] +
                 pacc[mi][ni][2] * acc[mi][ni][2] + pacc[mi][ni][3] * acc[mi][ni][3];
      sr += __shfl_xor(sr, 16, 64);
      if ((lane & 16) == 0) {
        int node = (row0 >> 3) + wm * 8 + mi * 2 + (lane >> 5);
        int col = wn * 64 + ni * 16 + (lane & 15);
        vdot[(size_t)node * 128 + col] = sr;
      }
    }
  }
}

// ---------------- mega GEMM: big (bid<1896) | qkv (<2136) | fm (<3648) ----------------
__global__ __launch_bounds__(256, 3) void gemm_multi(
    const __bf16* __restrict__ vecw, const __bf16* __restrict__ xln,
    const __bf16* __restrict__ fijb, const __bf16* __restrict__ Wt,
    const float* __restrict__ bqkv, const float* __restrict__ bfm,
    __bf16* __restrict__ vec3, __bf16* __restrict__ vtT, __bf16* __restrict__ vsT,
    __bf16* __restrict__ qkv, __bf16* __restrict__ fm) {
  __shared__ __bf16 As[128 * 128];
  __bf16* Cs = As;
  const int tid = threadIdx.x;
  const int lane = tid & 63;
  const int wave = tid >> 6;
  const int wm = wave >> 1, wn = wave & 1;

  int bid = blockIdx.x;
  const __bf16* A;
  const __bf16* Bt;
  const float* bias = nullptr;
  __bf16* C = nullptr;
  int nx, ny, M, ldc = 384, act = 0, big = 0;
  if (bid < 1896) {
    A = vecw; Bt = Wt + (size_t)256 * 128; nx = 625; ny = 3; M = NL; big = 1;
  } else if (bid < 2136) {
    bid -= 1896;
    A = xln; Bt = Wt + (size_t)640 * 128; bias = bqkv; C = qkv; nx = 79; ny = 3; M = N_NODES;
  } else {
    bid -= 2136;
    A = fijb; Bt = Wt + (size_t)1024 * 128; bias = bfm; C = fm; nx = 500; ny = 3; M = N_EDGES;
    act = 1;
  }

  const int xi = bid & 7;
  const int rem = bid >> 3;
  const int y = rem % ny;
  const int x = (rem / ny) * 8 + xi;
  if (x >= nx) return;
  const int row0 = x * 128;

#pragma unroll
  for (int i = 0; i < 8; ++i) {
    int c = tid + i * 256;
    int row = c >> 4, k8 = c & 15;
    int k8s = k8 ^ (row & 7);
    const __bf16* src = A + (size_t)(row0 + row) * 128 + k8s * 8;
    __builtin_amdgcn_global_load_lds((const __attribute__((address_space(1))) void*)src,
                                     (__attribute__((address_space(3))) void*)(As + c * 8),
                                     16, 0, 0);
  }
  __syncthreads();

  const __bf16* Bbase =
      Bt + ((size_t)(y * 128 + wn * 64 + (lane & 15)) << 7) + ((lane >> 4) << 3);
  bf16x8 b[4][4];
#pragma unroll
  for (int ks = 0; ks < 4; ++ks)
#pragma unroll
    for (int ni = 0; ni < 4; ++ni) b[ks][ni] = *(const bf16x8*)(Bbase + (ni << 11) + (ks << 5));

  f32x4 acc[4][4];
#pragma unroll
  for (int mi = 0; mi < 4; ++mi)
#pragma unroll
    for (int ni = 0; ni < 4; ++ni) acc[mi][ni] = f32x4{0.f, 0.f, 0.f, 0.f};

#pragma unroll
  for (int ks = 0; ks < 4; ++ks) {
    bf16x8 a[4];
#pragma unroll
    for (int mi = 0; mi < 4; ++mi) {
      int row = wm * 64 + mi * 16 + (lane & 15);
      int byte = (row * 256 + ks * 64 + ((lane >> 4) << 4)) ^ ((row & 7) << 4);
      a[mi] = *(const bf16x8*)((const char*)As + byte);
    }
#pragma unroll
    for (int mi = 0; mi < 4; ++mi)
#pragma unroll
      for (int ni = 0; ni < 4; ++ni)
        acc[mi][ni] =
            __builtin_amdgcn_mfma_f32_16x16x32_bf16(a[mi], b[ks][ni], acc[mi][ni], 0, 0, 0);
  }

  if (big) {
    __bf16* T = (y == 1) ? vtT : vsT;
#pragma unroll
    for (int p = 0; p < 2; ++p) {
      __syncthreads();
      int rl = (wm << 5) | ((lane >> 4) << 2);
#pragma unroll
      for (int q = 0; q < 2; ++q) {
        int mi = 2 * p + q;
#pragma unroll
        for (int ni = 0; ni < 4; ++ni) {
          int col = wn * 64 + ni * 16 + (lane & 15);
#pragma unroll
          for (int r = 0; r < 4; ++r)
            Cs[(rl + q * 16 + r) * 136 + col] = (__bf16)acc[mi][ni][r];
        }
      }
      __syncthreads();
      if (y == 0) {
#pragma unroll
        for (int rr = 0; rr < 4; ++rr) {
          int row = (tid >> 4) + rr * 16;
          int chunk = tid & 15;
          bf16x8 v = *(const bf16x8*)(Cs + row * 136 + chunk * 8);
          int grow = row0 + (row >> 5) * 64 + (2 * p + ((row >> 4) & 1)) * 16 + (row & 15);
          *(bf16x8*)(vec3 + (size_t)grow * 128 + chunk * 8) = v;
        }
      } else {
#pragma unroll
        for (int j = 0; j < 4; ++j) {
          int idx = tid + 256 * j;
          int node_idx = idx >> 7;  // 0..7
          int h = idx & 127;
          int wmm = node_idx >> 2, qq = (node_idx >> 1) & 1, w = node_idx & 1;
          int base = wmm * 32 + qq * 16 + w * 8;
          bf16x8 v;
#pragma unroll
          for (int l = 0; l < 8; ++l) v[l] = Cs[(base + l) * 136 + h];
          int g = (row0 >> 3) + wmm * 8 + (2 * p + qq) * 2 + w;
          *(bf16x8*)(T + (size_t)g * 1024 + h * 8) = v;
        }
      }
    }
  } else {
    const int cstore = y * 128;
#pragma unroll
    for (int p = 0; p < 2; ++p) {
      __syncthreads();
      int rl = (wm << 5) | ((lane >> 4) << 2);
#pragma unroll
      for (int q = 0; q < 2; ++q) {
        int mi = 2 * p + q;
#pragma unroll
        for (int ni = 0; ni < 4; ++ni) {
          int col = wn * 64 + ni * 16 + (lane & 15);
          float bv = bias[cstore + col];
#pragma unroll
          for (int r = 0; r < 4; ++r) {
            float xv = acc[mi][ni][r] + bv;
            if (act) xv = silu_f(xv);
            Cs[(rl + q * 16 + r) * 136 + col] = (__bf16)xv;
          }
        }
      }
      __syncthreads();
#pragma unroll
      for (int rr = 0; rr < 4; ++rr) {
        int row = (tid >> 4) + rr * 16;
        int chunk = tid & 15;
        bf16x8 v = *(const bf16x8*)(Cs + row * 136 + chunk * 8);
        int grow = row0 + (row >> 5) * 64 + (2 * p + ((row >> 4) & 1)) * 16 + (row & 15);
        if (grow < M)
          *(bf16x8*)(C + (size_t)grow * ldc + cstore + chunk * 8) = v;
      }
    }
  }
}

// ---------------- MFMA GEMM v9 (s-GEMM): bf16-A, XCD-swizzled ----------------
template <typename CT>
__global__ __launch_bounds__(256, 3) void gemm_v9(const __bf16* __restrict__ A,
                                                  const __bf16* __restrict__ Bt,
                                                  const float* __restrict__ bias,
                                                  CT* __restrict__ C, int M, int nx, int ny,
                                                  int ldc, int act) {
  __shared__ __bf16 As[128 * 128];
  __bf16* Cs = As;
  const int bid = blockIdx.x;
  const int xi = bid & 7;
  const int rem = bid >> 3;
  const int y = rem % ny;
  const int x = (rem / ny) * 8 + xi;
  if (x >= nx) return;
  const int tid = threadIdx.x;
  const int lane = tid & 63;
  const int wave = tid >> 6;
  const int wm = wave >> 1, wn = wave & 1;
  const int row0 = x * 128;

#pragma unroll
  for (int i = 0; i < 8; ++i) {
    int c = tid + i * 256;
    int row = c >> 4, k8 = c & 15;
    int k8s = k8 ^ (row & 7);
    const __bf16* src = A + (size_t)(row0 + row) * 128 + k8s * 8;
    __builtin_amdgcn_global_load_lds((const __attribute__((address_space(1))) void*)src,
                                     (__attribute__((address_space(3))) void*)(As + c * 8),
                                     16, 0, 0);
  }
  __syncthreads();

  const __bf16* Bbase =
      Bt + ((size_t)(y * 128 + wn * 64 + (lane & 15)) << 7) + ((lane >> 4) << 3);
  bf16x8 b[4][4];
#pragma unroll
  for (int ks = 0; ks < 4; ++ks)
#pragma unroll
    for (int ni = 0; ni < 4; ++ni) b[ks][ni] = *(const bf16x8*)(Bbase + (ni << 11) + (ks << 5));

  f32x4 acc[4][4];
#pragma unroll
  for (int mi = 0; mi < 4; ++mi)
#pragma unroll
    for (int ni = 0; ni < 4; ++ni) acc[mi][ni] = f32x4{0.f, 0.f, 0.f, 0.f};

#pragma unroll
  for (int ks = 0; ks < 4; ++ks) {
    bf16x8 a[4];
#pragma unroll
    for (int mi = 0; mi < 4; ++mi) {
      int row = wm * 64 + mi * 16 + (lane & 15);
      int byte = (row * 256 + ks * 64 + ((lane >> 4) << 4)) ^ ((row & 7) << 4);
      a[mi] = *(const bf16x8*)((const char*)As + byte);
    }
#pragma unroll
    for (int mi = 0; mi < 4; ++mi)
#pragma unroll
      for (int ni = 0; ni < 4; ++ni)
        acc[mi][ni] =
            __builtin_amdgcn_mfma_f32_16x16x32_bf16(a[mi], b[ks][ni], acc[mi][ni], 0, 0, 0);
  }

  const int cstore = y * 128;
#pragma unroll
  for (int p = 0; p < 2; ++p) {
    __syncthreads();
    int rl = (wm << 5) | ((lane >> 4) << 2);
#pragma unroll
    for (int q = 0; q < 2; ++q) {
      int mi = 2 * p + q;
#pragma unroll
      for (int ni = 0; ni < 4; ++ni) {
        int col = wn * 64 + ni * 16 + (lane & 15);
        float bv = bias ? bias[cstore + col] : 0.f;
#pragma unroll
        for (int r = 0; r < 4; ++r) {
          float xv = acc[mi][ni][r] + bv;
          if (act) xv = silu_f(xv);
          Cs[(rl + q * 16 + r) * 136 + col] = (__bf16)xv;
        }
      }
    }
    __syncthreads();
#pragma unroll
    for (int rr = 0; rr < 4; ++rr) {
      int row = (tid >> 4) + rr * 16;
      int chunk = tid & 15;
      bf16x8 v = *(const bf16x8*)(Cs + row * 136 + chunk * 8);
      int grow = row0 + (row >> 5) * 64 + (2 * p + ((row >> 4) & 1)) * 16 + (row & 15);
      if (grow < M)
        *(bf16x8*)(C + (size_t)grow * ldc + cstore + chunk * 8) = v;
    }
  }
}

// ---------------- o-GEMM fused with final: 79 blocks, full 384-col tile in LDS ----------
// o = xagg @ Wo + b_o; then dx = vdot*o2+o3, dvec = avb + vec3*o1 (write-only).
__global__ __launch_bounds__(256, 1) void gemm_ofinal(
    const __bf16* __restrict__ A,     // xagg [N][128]
    const __bf16* __restrict__ Bt,    // Wt rows 1664..2048
    const float* __restrict__ bias,   // b_o [384]
    const float* __restrict__ vdot,   // [N][128]
    const __bf16* __restrict__ vec3,  // [NL][128]
    const __bf16* __restrict__ avb,   // [N][1024]
    float* __restrict__ dx, float* __restrict__ dvec) {
  __shared__ __bf16 As[128 * 128];   // 32 KB
  __shared__ __bf16 Os[128 * 392];   // 98 KB (row-major o tile, padded)
  const int tid = threadIdx.x;
  const int lane = tid & 63;
  const int wave = tid >> 6;
  const int wm = wave >> 1, wn = wave & 1;
  const int row0 = blockIdx.x * 128;

#pragma unroll
  for (int i = 0; i < 8; ++i) {
    int c = tid + i * 256;
    int row = c >> 4, k8 = c & 15;
    int k8s = k8 ^ (row & 7);
    const __bf16* src = A + (size_t)(row0 + row) * 128 + k8s * 8;
    __builtin_amdgcn_global_load_lds((const __attribute__((address_space(1))) void*)src,
                                     (__attribute__((address_space(3))) void*)(As + c * 8),
                                     16, 0, 0);
  }
  __syncthreads();

#pragma unroll
  for (int ct = 0; ct < 3; ++ct) {
    const __bf16* Bbase =
        Bt + ((size_t)(ct * 128 + wn * 64 + (lane & 15)) << 7) + ((lane >> 4) << 3);
    bf16x8 b[4][4];
#pragma unroll
    for (int ks = 0; ks < 4; ++ks)
#pragma unroll
      for (int ni = 0; ni < 4; ++ni) b[ks][ni] = *(const bf16x8*)(Bbase + (ni << 11) + (ks << 5));

    f32x4 acc[4][4];
#pragma unroll
    for (int mi = 0; mi < 4; ++mi)
#pragma unroll
      for (int ni = 0; ni < 4; ++ni) acc[mi][ni] = f32x4{0.f, 0.f, 0.f, 0.f};

#pragma unroll
    for (int ks = 0; ks < 4; ++ks) {
      bf16x8 a[4];
#pragma unroll
      for (int mi = 0; mi < 4; ++mi) {
        int row = wm * 64 + mi * 16 + (lane & 15);
        int byte = (row * 256 + ks * 64 + ((lane >> 4) << 4)) ^ ((row & 7) << 4);
        a[mi] = *(const bf16x8*)((const char*)As + byte);
      }
#pragma unroll
      for (int mi = 0; mi < 4; ++mi)
#pragma unroll
        for (int ni = 0; ni < 4; ++ni)
          acc[mi][ni] =
              __builtin_amdgcn_mfma_f32_16x16x32_bf16(a[mi], b[ks][ni], acc[mi][ni], 0, 0, 0);
    }

    // write this ct's 128x128 result (natural row index) into Os at col offset ct*128
#pragma unroll
    for (int mi = 0; mi < 4; ++mi) {
      int rbase = wm * 64 + mi * 16 + ((lane >> 4) << 2);
#pragma unroll
      for (int ni = 0; ni < 4; ++ni) {
        int col = ct * 128 + wn * 64 + ni * 16 + (lane & 15);
        float bv = bias[col];
#pragma unroll
        for (int r = 0; r < 4; ++r)
          Os[(rbase + r) * 392 + col] = (__bf16)(acc[mi][ni][r] + bv);
      }
    }
  }
  __syncthreads();

  // consume: 128 rows x 128 h; 64 items per thread
#pragma unroll
  for (int i = 0; i < 64; ++i) {
    int idx = tid + i * 256;
    int rloc = idx >> 7;  // 0..127 (natural row)
    int h = idx & 127;
    int n = row0 + rloc;
    if (n < N_NODES) {
      float o1 = (float)Os[rloc * 392 + h];
      float o2 = (float)Os[rloc * 392 + 128 + h];
      float o3 = (float)Os[rloc * 392 + 256 + h];
      dx[(size_t)n * H + h] = vdot[(size_t)n * 128 + h] * o2 + o3;
      bf16x8 av8 = *(const bf16x8*)(avb + (size_t)n * 1024 + h * 8);
      const __bf16* v3 = vec3 + (size_t)n * 1024 + h;
      float* drow = dvec + (size_t)n * 1024 + h;
#pragma unroll
      for (int l = 0; l < L; l++) drow[l * 128] = (float)av8[l] + (float)v3[l * 128] * o1;
    }
  }
}

// helper: swizzled grid size
static inline int swz_grid(int nx, int ny) { return ((nx + 7) / 8) * ny * 8; }

// ---------------- message (fully p-indexed): attn + vm[p] ----------------
__global__ __launch_bounds__(256) void msg_kernel(const __bf16* __restrict__ qkv,
                                                  const __bf16* __restrict__ fm,
                                                  const float* __restrict__ r2,
                                                  const int* __restrict__ srclist,
                                                  const int* __restrict__ dstlist,
                                                  __bf16* __restrict__ vm) {
  int p = blockIdx.x * 2 + (threadIdx.x >> 7);
  int h = threadIdx.x & 127;
  int src = srclist[p], dst = dstlist[p];
  float qv = (float)qkv[(size_t)dst * 384 + h];
  float kv = (float)qkv[(size_t)src * 384 + 128 + h];
  float vv = (float)qkv[(size_t)src * 384 + 256 + h];
  float t = qv * kv * (float)fm[(size_t)p * 384 + h];
#pragma unroll
  for (int off = 8; off >= 1; off >>= 1) t += __shfl_xor(t, off, 16);
  float r = r2[p];
  float cut = 0.5f * (__cosf(0.6283185307f * r) + 1.f);
  cut = (r < 5.f) ? cut : 0.f;
  float attn = silu_f(t) * cut;
  vm[(size_t)p * H + h] = (__bf16)(vv * (float)fm[(size_t)p * 384 + 128 + h] * attn);
}

// ---------------- CSR build: histogram, scan, fill ----------------
__global__ __launch_bounds__(256) void hist_kernel(const int* __restrict__ ei,
                                                   int* __restrict__ cnt) {
  int e = blockIdx.x * 256 + threadIdx.x;
  if (e < N_EDGES) atomicAdd(&cnt[ei[N_EDGES + e]], 1);
}

__global__ __launch_bounds__(1024) void scan_kernel(const int* __restrict__ cnt,
                                                    int* __restrict__ rowptr) {
  __shared__ int wsum[16];
  int t = threadIdx.x;
  int base = t * 10;
  int local[10];
  int s = 0;
#pragma unroll
  for (int i = 0; i < 10; ++i) {
    int v = (base + i < N_NODES) ? cnt[base + i] : 0;
    local[i] = s;
    s += v;
  }
  int lane = t & 63, wave = t >> 6;
  int inc = s;
#pragma unroll
  for (int off = 1; off < 64; off <<= 1) {
    int u = __shfl_up(inc, off, 64);
    if (lane >= off) inc += u;
  }
  if (lane == 63) wsum[wave] = inc;
  __syncthreads();
  if (t == 0) {
    int acc = 0;
#pragma unroll
    for (int w = 0; w < 16; ++w) { int v = wsum[w]; wsum[w] = acc; acc += v; }
  }
  __syncthreads();
  int excl = inc - s + wsum[wave];
#pragma unroll
  for (int i = 0; i < 10; ++i)
    if (base + i <= N_NODES) rowptr[base + i] = excl + local[i];
}

__global__ __launch_bounds__(256) void fill_kernel(const int* __restrict__ ei,
                                                   const int* __restrict__ rowptr,
                                                   int* __restrict__ cursor,
                                                   int* __restrict__ elist,
                                                   int* __restrict__ srclist,
                                                   int* __restrict__ dstlist) {
  int e = blockIdx.x * 256 + threadIdx.x;
  if (e < N_EDGES) {
    int s = ei[e];
    int d = ei[N_EDGES + e];
    int p = atomicAdd(&cursor[d], 1);
    int idx = rowptr[d] + p;
    elist[idx] = e;
    srclist[idx] = s;
    dstlist[idx] = d;
  }
}

// ---------------- node kernel: gather + edge update; ONE node per 128-thread block ----------
__global__ __launch_bounds__(128) void node_kernel(const __bf16* __restrict__ vm,
                                                   const __bf16* __restrict__ s,
                                                   const __bf16* __restrict__ vecwT,
                                                   const __bf16* __restrict__ vtT,
                                                   const __bf16* __restrict__ vsT,
                                                   const __bf16* __restrict__ fm,
                                                   const float* __restrict__ d2,
                                                   const int* __restrict__ srclist,
                                                   const int* __restrict__ elist,
                                                   const int* __restrict__ rowptr,
                                                   __bf16* __restrict__ x_agg,
                                                   __bf16* __restrict__ avb,
                                                   float* __restrict__ df) {
  int n = blockIdx.x;
  int h = threadIdx.x;  // 0..127
  int beg = rowptr[n], end = rowptr[n + 1];

  bf16x8 vt8 = *(const bf16x8*)(vtT + (size_t)n * 1024 + h * 8);
  float vt[L];
#pragma unroll
  for (int l = 0; l < L; l++) vt[l] = (float)vt8[l];

  float ax = 0.f;
  float av[L] = {};
  for (int p = beg; p < end; ++p) {
    int src = srclist[p];
    const float* dd = d2 + (size_t)p * L;
    float d[L], sd2 = 0.f;
#pragma unroll
    for (int l = 0; l < L; l++) {
      d[l] = dd[l];
      sd2 += d[l] * d[l];
    }
    ax += (float)vm[(size_t)p * H + h];
    float s1 = (float)s[(size_t)p * 256 + h];
    float s2 = (float)s[(size_t)p * 256 + 128 + h];
    bf16x8 vw8 = *(const bf16x8*)(vecwT + (size_t)src * 1024 + h * 8);
    bf16x8 vs8 = *(const bf16x8*)(vsT + (size_t)src * 1024 + h * 8);
    float dot = 0.f, p1 = 0.f, p2 = 0.f;
#pragma unroll
    for (int l = 0; l < L; l++) {
      av[l] += (float)vw8[l] * s1 + s2 * d[l];
      float bb = (float)vs8[l];
      dot += vt[l] * bb;
      p1 += vt[l] * d[l];
      p2 += bb * d[l];
    }
    float wdot = dot - p1 * p2 * (2.f - sd2);
    df[(size_t)elist[p] * H + h] = (float)fm[(size_t)p * 384 + 256 + h] * wdot;
  }
  x_agg[(size_t)n * H + h] = (__bf16)ax;
  bf16x8 pack;
#pragma unroll
  for (int l = 0; l < L; l++) pack[l] = (__bf16)av[l];
  *(bf16x8*)(avb + (size_t)n * 1024 + h * 8) = pack;
}

extern "C" void kernel_launch(void* const* d_in, const int* in_sizes, int n_in, void* d_out,
                              int out_size, void* d_ws, size_t ws_size, hipStream_t stream) {
  const float* x = (const float*)d_in[0];
  const float* vec = (const float*)d_in[1];
  const float* f_ij = (const float*)d_in[2];
  const float* d_ij = (const float*)d_in[3];
  const float* r_ij = (const float*)d_in[4];
  const int* ei = (const int*)d_in[5];
  const float* ln_g = (const float*)d_in[6];
  const float* ln_b = (const float*)d_in[7];
  const float* vln_w = (const float*)d_in[8];
  const float* W_vec = (const float*)d_in[9];
  const float* W_q = (const float*)d_in[10];
  const float* b_q = (const float*)d_in[11];
  const float* W_k = (const float*)d_in[12];
  const float* b_k = (const float*)d_in[13];
  const float* W_v = (const float*)d_in[14];
  const float* b_v = (const float*)d_in[15];
  const float* W_dk = (const float*)d_in[16];
  const float* b_dk = (const float*)d_in[17];
  const float* W_dv = (const float*)d_in[18];
  const float* b_dv = (const float*)d_in[19];
  const float* W_s = (const float*)d_in[20];
  const float* b_s = (const float*)d_in[21];
  const float* W_f = (const float*)d_in[22];
  const float* b_f = (const float*)d_in[23];
  const float* W_src = (const float*)d_in[24];
  const float* W_trg = (const float*)d_in[25];
  const float* W_o = (const float*)d_in[26];
  const float* b_o = (const float*)d_in[27];

  float* out = (float*)d_out;
  float* dx = out;
  float* dvec = out + (size_t)N_NODES * H;
  float* df = dvec + (size_t)N_NODES * L * H;

  // ---- workspace plan (offsets in f32 slots; ~268 MB) ----
  float* ws = (float*)d_ws;
  __bf16* vecw = (__bf16*)ws;                 // NL*128 bf16
  __bf16* vec3 = (__bf16*)(ws + 5120000);     // NL*128 bf16
  __bf16* vtT = (__bf16*)(ws + 10240000);     // N*1024 bf16 [n][h][8]
  __bf16* vsT = (__bf16*)(ws + 15360000);     // N*1024 bf16
  __bf16* fm = (__bf16*)(ws + 20480000);      // E*384 bf16 (p-order)
  __bf16* vm = (__bf16*)(ws + 32768000);      // E*128 bf16 (p-order)
  __bf16* s_buf = (__bf16*)(ws + 36864000);   // E*256 bf16 (p-order)
  __bf16* qkv = (__bf16*)(ws + 45056000);     // N*384 bf16
  __bf16* xln = (__bf16*)(ws + 48896000);     // N*128 bf16 (+tail slack)
  __bf16* xagg = (__bf16*)(ws + 49536000);    // N*128 bf16 (+tail slack)
  float* vdot = ws + 50176000;                // N*128 f32
  __bf16* Wt = (__bf16*)(ws + 51456000);      // [2048][128] bf16
  float* bqkv = ws + 51456000 + 131072;       // 384
  float* bfm = bqkv + 384;                    // 384
  int* rowptr = (int*)(bfm + 384);            // 10,001
  int* elist = rowptr + 10001;                // 64,000
  int* srclist = elist + 64000;               // 64,000
  int* dstlist = srclist + 64000;             // 64,000
  int* cnt = dstlist + 64000;                 // 10,000
  int* cursor = cnt + 10000;                  // 10,000 (adjacent: single memset)
  __bf16* fijb = (__bf16*)(ws + 51900000);    // E*128 bf16 (p-order)
  __bf16* vecwT = (__bf16*)(ws + 56000000);   // N*1024 bf16 [n][h][8]
  float* d2 = ws + 61200000;                  // E*8 f32 (p-order)
  float* r2 = ws + 61712000;                  // E f32 (p-order)
  __bf16* avb = (__bf16*)(ws + 61776000);     // N*1024 bf16 [n][h][8]

  dim3 b256(256);

  // CSR build (depends only on ei)
  hipMemsetAsync(cnt, 0, 2 * N_NODES * sizeof(int), stream);
  hist_kernel<<<dim3((N_EDGES + 255) / 256), b256, 0, stream>>>(ei, cnt);
  scan_kernel<<<dim3(1), dim3(1024), 0, stream>>>(cnt, rowptr);
  fill_kernel<<<dim3((N_EDGES + 255) / 256), b256, 0, stream>>>(ei, rowptr, cursor, elist,
                                                                srclist, dstlist);
  // prep2: wconv + biases + vecw/vecwT + ln + fgather + dgather (one launch, after fill)
  prep2_kernel<<<dim3(17758), b256, 0, stream>>>(
      W_vec, W_q, W_k, W_v, W_dk, W_dv, W_s, W_trg, W_src, W_f, W_o, b_q, b_k, b_v, b_dk,
      b_dv, b_f, Wt, bqkv, bfm, x, ln_g, ln_b, xln, vec, vln_w, vecw, vecwT, f_ij, d_ij,
      r_ij, elist, fijb, d2, r2);

  // vdot (dedicated, no-spill kernel; Wt rows 0..255 = vec1|vec2)
  vdot_gemm<<<dim3(625), b256, 0, stream>>>(vecw, Wt, vdot);

  // mega GEMM: big (vec3|vtT|vsT) + qkv + fm in one launch
  gemm_multi<<<dim3(1896 + 240 + 1512), b256, 0, stream>>>(vecw, xln, fijb, Wt, bqkv, bfm,
                                                           vec3, vtT, vsT, qkv, fm);

  // message -> vm[p] (fully p-indexed)
  msg_kernel<<<dim3(N_EDGES / 2), b256, 0, stream>>>(qkv, fm, r2, srclist, dstlist, vm);
  // s = silu(vm @ W_s + b) (p-order)
  gemm_v9<__bf16><<<dim3(swz_grid(500, 2)), b256, 0, stream>>>(
      vm, Wt + (size_t)1408 * 128, b_s, s_buf, N_EDGES, 500, 2, 256, 1);
  // node-major: one node per 128-thread block; av -> bf16 avb
  node_kernel<<<dim3(N_NODES), dim3(128), 0, stream>>>(vm, s_buf, vecwT, vtT, vsT, fm, d2,
                                                       srclist, elist, rowptr, xagg, avb, df);
  // o-GEMM fused with final: dx, dvec written directly
  gemm_ofinal<<<dim3(79), b256, 0, stream>>>(xagg, Wt + (size_t)1664 * 128, b_o, vdot, vec3,
                                             avb, dx, dvec);
}

// Round 23
// 261.552 us; speedup vs baseline: 1.1427x; 1.1427x over previous
//
#include <hip/hip_runtime.h>
#include <hip/hip_bf16.h>
#include <math.h>

#define N_NODES 10000
#define N_EDGES 64000
#define H 128
#define L 8
#define NL (N_NODES * L)

typedef __attribute__((ext_vector_type(4))) float f32x4;
typedef __attribute__((ext_vector_type(8))) __bf16 bf16x8;
typedef __attribute__((ext_vector_type(4))) __bf16 bf16x4;

__device__ __forceinline__ float silu_f(float x) { return x / (1.f + __expf(-x)); }

// ---------------- prep2: wconv+bias | vecw | ln | fgather | dgather (one launch) ----------
__global__ __launch_bounds__(256) void prep2_kernel(
    const float* __restrict__ Wvec, const float* __restrict__ Wq, const float* __restrict__ Wk,
    const float* __restrict__ Wv, const float* __restrict__ Wdk, const float* __restrict__ Wdv,
    const float* __restrict__ Ws, const float* __restrict__ Wtrg, const float* __restrict__ Wsrc,
    const float* __restrict__ Wf, const float* __restrict__ Wo,
    const float* __restrict__ bq, const float* __restrict__ bk, const float* __restrict__ bv,
    const float* __restrict__ bdk, const float* __restrict__ bdv, const float* __restrict__ bf,
    __bf16* __restrict__ Wt, float* __restrict__ bqkv, float* __restrict__ bfm,
    const float* __restrict__ x, const float* __restrict__ g, const float* __restrict__ b,
    __bf16* __restrict__ xln, const float* __restrict__ vec, const float* __restrict__ w,
    __bf16* __restrict__ vecw, __bf16* __restrict__ vecwT,
    const float* __restrict__ fin, const float* __restrict__ d_ij,
    const float* __restrict__ r_ij, const int* __restrict__ elist,
    __bf16* __restrict__ fout, float* __restrict__ d2, float* __restrict__ r2) {
  __shared__ float tile[32][33];
  int bid = blockIdx.x;
  int t = threadIdx.x;
  if (bid < 256) {
    int ct = bid >> 2, kt = bid & 3;
    int gc0 = ct * 32;
    const float* W; int ldw, sc0;
    if      (gc0 < 384)  { W = Wvec; ldw = 384; sc0 = gc0; }
    else if (gc0 < 512)  { W = Wtrg; ldw = 128; sc0 = gc0 - 384; }
    else if (gc0 < 640)  { W = Wsrc; ldw = 128; sc0 = gc0 - 512; }
    else if (gc0 < 768)  { W = Wq;   ldw = 128; sc0 = gc0 - 640; }
    else if (gc0 < 896)  { W = Wk;   ldw = 128; sc0 = gc0 - 768; }
    else if (gc0 < 1024) { W = Wv;   ldw = 128; sc0 = gc0 - 896; }
    else if (gc0 < 1152) { W = Wdk;  ldw = 128; sc0 = gc0 - 1024; }
    else if (gc0 < 1280) { W = Wdv;  ldw = 128; sc0 = gc0 - 1152; }
    else if (gc0 < 1408) { W = Wf;   ldw = 128; sc0 = gc0 - 1280; }
    else if (gc0 < 1664) { W = Ws;   ldw = 256; sc0 = gc0 - 1408; }
    else                 { W = Wo;   ldw = 384; sc0 = gc0 - 1664; }
    int tx = t & 31, ty = t >> 5;
#pragma unroll
    for (int i = 0; i < 4; ++i)
      tile[ty + i * 8][tx] = W[(size_t)(kt * 32 + ty + i * 8) * ldw + sc0 + tx];
    __syncthreads();
#pragma unroll
    for (int i = 0; i < 4; ++i)
      Wt[(size_t)(gc0 + ty + i * 8) * 128 + kt * 32 + tx] = (__bf16)tile[tx][ty + i * 8];
  } else if (bid == 256) {
    if (t < 128) { bqkv[t] = bq[t]; bqkv[128 + t] = bk[t]; bqkv[256 + t] = bv[t]; }
  } else if (bid == 257) {
    if (t < 128) { bfm[t] = bdk[t]; bfm[128 + t] = bdv[t]; bfm[256 + t] = bf[t]; }
  } else if (bid < 258 + 5000) {
    int n = (bid - 258) * 2 + (t >> 7);
    int h = t & 127;
    float wl = w[h];
    const float* base = vec + (size_t)n * 1024 + h;
    __bf16* orow = vecw + (size_t)n * 1024 + h;
    bf16x8 pack;
#pragma unroll
    for (int l = 0; l < 8; ++l) {
      __bf16 bv = (__bf16)(base[l * 128] * wl);
      orow[l * 128] = bv;
      pack[l] = bv;
    }
    *(bf16x8*)(vecwT + (size_t)n * 1024 + h * 8) = pack;
  } else if (bid < 258 + 5000 + 2500) {
    int wave = t >> 6;
    int lane = t & 63;
    int n = (bid - 258 - 5000) * 4 + wave;
    if (n >= N_NODES) return;
    const float* xr = x + (size_t)n * H;
    float a0 = xr[lane], a1 = xr[lane + 64];
    float s = a0 + a1;
#pragma unroll
    for (int off = 32; off >= 1; off >>= 1) s += __shfl_xor(s, off, 64);
    float mu = s * (1.f / H);
    float d0 = a0 - mu, d1 = a1 - mu;
    float v = d0 * d0 + d1 * d1;
#pragma unroll
    for (int off = 32; off >= 1; off >>= 1) v += __shfl_xor(v, off, 64);
    float rstd = rsqrtf(v * (1.f / H) + 1e-5f);
    __bf16* orow = xln + (size_t)n * H;
    orow[lane] = (__bf16)(d0 * rstd * g[lane] + b[lane]);
    orow[lane + 64] = (__bf16)(d1 * rstd * g[lane + 64] + b[lane + 64]);
  } else if (bid < 258 + 5000 + 2500 + 8000) {
    int p = (bid - 7758) * 8 + (t >> 5);
    int c = (t & 31) * 4;
    int e = elist[p];
    f32x4 a = *(const f32x4*)(fin + (size_t)e * 128 + c);
    bf16x4 h;
    h[0] = (__bf16)a[0]; h[1] = (__bf16)a[1]; h[2] = (__bf16)a[2]; h[3] = (__bf16)a[3];
    *(bf16x4*)(fout + (size_t)p * 128 + c) = h;
  } else {
    int idx = (bid - 15758) * 256 + t;  // over E*8
    int p = idx >> 3, j = idx & 7;
    int e = elist[p];
    d2[idx] = d_ij[(size_t)e * 8 + j];
    if (j == 0) r2[p] = r_ij[e];
  }
}

// ---------------- vdot GEMM: dedicated kernel, no spill ----------------
__global__ __launch_bounds__(256, 2) void vdot_gemm(const __bf16* __restrict__ A,
                                                    const __bf16* __restrict__ Bt,
                                                    float* __restrict__ vdot) {
  __shared__ __bf16 As[128 * 128];
  const int tid = threadIdx.x;
  const int lane = tid & 63;
  const int wave = tid >> 6;
  const int wm = wave >> 1, wn = wave & 1;
  const int row0 = blockIdx.x * 128;

#pragma unroll
  for (int i = 0; i < 8; ++i) {
    int c = tid + i * 256;
    int row = c >> 4, k8 = c & 15;
    int k8s = k8 ^ (row & 7);
    const __bf16* src = A + (size_t)(row0 + row) * 128 + k8s * 8;
    __builtin_amdgcn_global_load_lds((const __attribute__((address_space(1))) void*)src,
                                     (__attribute__((address_space(3))) void*)(As + c * 8),
                                     16, 0, 0);
  }
  __syncthreads();

  f32x4 pacc[4][4], acc[4][4];
#pragma unroll
  for (int mi = 0; mi < 4; ++mi)
#pragma unroll
    for (int ni = 0; ni < 4; ++ni) {
      pacc[mi][ni] = f32x4{0.f, 0.f, 0.f, 0.f};
      acc[mi][ni] = f32x4{0.f, 0.f, 0.f, 0.f};
    }
#pragma unroll
  for (int ct = 0; ct < 2; ++ct) {
    const __bf16* Bbase =
        Bt + ((size_t)(ct * 128 + wn * 64 + (lane & 15)) << 7) + ((lane >> 4) << 3);
#pragma unroll
    for (int ks = 0; ks < 4; ++ks) {
      bf16x8 b[4];
#pragma unroll
      for (int ni = 0; ni < 4; ++ni) b[ni] = *(const bf16x8*)(Bbase + (ni << 11) + (ks << 5));
      bf16x8 a[4];
#pragma unroll
      for (int mi = 0; mi < 4; ++mi) {
        int row = wm * 64 + mi * 16 + (lane & 15);
        int byte = (row * 256 + ks * 64 + ((lane >> 4) << 4)) ^ ((row & 7) << 4);
        a[mi] = *(const bf16x8*)((const char*)As + byte);
      }
      if (ct == 0) {
#pragma unroll
        for (int mi = 0; mi < 4; ++mi)
#pragma unroll
          for (int ni = 0; ni < 4; ++ni)
            pacc[mi][ni] =
                __builtin_amdgcn_mfma_f32_16x16x32_bf16(a[mi], b[ni], pacc[mi][ni], 0, 0, 0);
      } else {
#pragma unroll
        for (int mi = 0; mi < 4; ++mi)
#pragma unroll
          for (int ni = 0; ni < 4; ++ni)
            acc[mi][ni] =
                __builtin_amdgcn_mfma_f32_16x16x32_bf16(a[mi], b[ni], acc[mi][ni], 0, 0, 0);
      }
    }
  }
#pragma unroll
  for (int mi = 0; mi < 4; ++mi) {
#pragma unroll
    for (int ni = 0; ni < 4; ++ni) {
      float sr = pacc[mi][ni][0] * acc[mi][ni][0] + pacc[mi][ni][1] * acc[mi][ni][1] +
                 pacc[mi][ni][2] * acc[mi][ni][2] + pacc[mi][ni][3] * acc[mi][ni][3];
      sr += __shfl_xor(sr, 16, 64);
      if ((lane & 16) == 0) {
        int node = (row0 >> 3) + wm * 8 + mi * 2 + (lane >> 5);
        int col = wn * 64 + ni * 16 + (lane & 15);
        vdot[(size_t)node * 128 + col] = sr;
      }
    }
  }
}

// ---------------- mega GEMM: big (bid<1896) | qkv (<2136) | fm (<3648) ----------------
__global__ __launch_bounds__(256, 3) void gemm_multi(
    const __bf16* __restrict__ vecw, const __bf16* __restrict__ xln,
    const __bf16* __restrict__ fijb, const __bf16* __restrict__ Wt,
    const float* __restrict__ bqkv, const float* __restrict__ bfm,
    __bf16* __restrict__ vec3, __bf16* __restrict__ vtT, __bf16* __restrict__ vsT,
    __bf16* __restrict__ qkv, __bf16* __restrict__ fm) {
  __shared__ __bf16 As[128 * 128];
  __bf16* Cs = As;
  const int tid = threadIdx.x;
  const int lane = tid & 63;
  const int wave = tid >> 6;
  const int wm = wave >> 1, wn = wave & 1;

  int bid = blockIdx.x;
  const __bf16* A;
  const __bf16* Bt;
  const float* bias = nullptr;
  __bf16* C = nullptr;
  int nx, ny, M, ldc = 384, act = 0, big = 0;
  if (bid < 1896) {
    A = vecw; Bt = Wt + (size_t)256 * 128; nx = 625; ny = 3; M = NL; big = 1;
  } else if (bid < 2136) {
    bid -= 1896;
    A = xln; Bt = Wt + (size_t)640 * 128; bias = bqkv; C = qkv; nx = 79; ny = 3; M = N_NODES;
  } else {
    bid -= 2136;
    A = fijb; Bt = Wt + (size_t)1024 * 128; bias = bfm; C = fm; nx = 500; ny = 3; M = N_EDGES;
    act = 1;
  }

  const int xi = bid & 7;
  const int rem = bid >> 3;
  const int y = rem % ny;
  const int x = (rem / ny) * 8 + xi;
  if (x >= nx) return;
  const int row0 = x * 128;

#pragma unroll
  for (int i = 0; i < 8; ++i) {
    int c = tid + i * 256;
    int row = c >> 4, k8 = c & 15;
    int k8s = k8 ^ (row & 7);
    const __bf16* src = A + (size_t)(row0 + row) * 128 + k8s * 8;
    __builtin_amdgcn_global_load_lds((const __attribute__((address_space(1))) void*)src,
                                     (__attribute__((address_space(3))) void*)(As + c * 8),
                                     16, 0, 0);
  }
  __syncthreads();

  const __bf16* Bbase =
      Bt + ((size_t)(y * 128 + wn * 64 + (lane & 15)) << 7) + ((lane >> 4) << 3);
  bf16x8 b[4][4];
#pragma unroll
  for (int ks = 0; ks < 4; ++ks)
#pragma unroll
    for (int ni = 0; ni < 4; ++ni) b[ks][ni] = *(const bf16x8*)(Bbase + (ni << 11) + (ks << 5));

  f32x4 acc[4][4];
#pragma unroll
  for (int mi = 0; mi < 4; ++mi)
#pragma unroll
    for (int ni = 0; ni < 4; ++ni) acc[mi][ni] = f32x4{0.f, 0.f, 0.f, 0.f};

#pragma unroll
  for (int ks = 0; ks < 4; ++ks) {
    bf16x8 a[4];
#pragma unroll
    for (int mi = 0; mi < 4; ++mi) {
      int row = wm * 64 + mi * 16 + (lane & 15);
      int byte = (row * 256 + ks * 64 + ((lane >> 4) << 4)) ^ ((row & 7) << 4);
      a[mi] = *(const bf16x8*)((const char*)As + byte);
    }
#pragma unroll
    for (int mi = 0; mi < 4; ++mi)
#pragma unroll
      for (int ni = 0; ni < 4; ++ni)
        acc[mi][ni] =
            __builtin_amdgcn_mfma_f32_16x16x32_bf16(a[mi], b[ks][ni], acc[mi][ni], 0, 0, 0);
  }

  if (big) {
    __bf16* T = (y == 1) ? vtT : vsT;
#pragma unroll
    for (int p = 0; p < 2; ++p) {
      __syncthreads();
      int rl = (wm << 5) | ((lane >> 4) << 2);
#pragma unroll
      for (int q = 0; q < 2; ++q) {
        int mi = 2 * p + q;
#pragma unroll
        for (int ni = 0; ni < 4; ++ni) {
          int col = wn * 64 + ni * 16 + (lane & 15);
#pragma unroll
          for (int r = 0; r < 4; ++r)
            Cs[(rl + q * 16 + r) * 136 + col] = (__bf16)acc[mi][ni][r];
        }
      }
      __syncthreads();
      if (y == 0) {
#pragma unroll
        for (int rr = 0; rr < 4; ++rr) {
          int row = (tid >> 4) + rr * 16;
          int chunk = tid & 15;
          bf16x8 v = *(const bf16x8*)(Cs + row * 136 + chunk * 8);
          int grow = row0 + (row >> 5) * 64 + (2 * p + ((row >> 4) & 1)) * 16 + (row & 15);
          *(bf16x8*)(vec3 + (size_t)grow * 128 + chunk * 8) = v;
        }
      } else {
#pragma unroll
        for (int j = 0; j < 4; ++j) {
          int idx = tid + 256 * j;
          int node_idx = idx >> 7;  // 0..7
          int h = idx & 127;
          int wmm = node_idx >> 2, qq = (node_idx >> 1) & 1, w = node_idx & 1;
          int base = wmm * 32 + qq * 16 + w * 8;
          bf16x8 v;
#pragma unroll
          for (int l = 0; l < 8; ++l) v[l] = Cs[(base + l) * 136 + h];
          int g = (row0 >> 3) + wmm * 8 + (2 * p + qq) * 2 + w;
          *(bf16x8*)(T + (size_t)g * 1024 + h * 8) = v;
        }
      }
    }
  } else {
    const int cstore = y * 128;
#pragma unroll
    for (int p = 0; p < 2; ++p) {
      __syncthreads();
      int rl = (wm << 5) | ((lane >> 4) << 2);
#pragma unroll
      for (int q = 0; q < 2; ++q) {
        int mi = 2 * p + q;
#pragma unroll
        for (int ni = 0; ni < 4; ++ni) {
          int col = wn * 64 + ni * 16 + (lane & 15);
          float bv = bias[cstore + col];
#pragma unroll
          for (int r = 0; r < 4; ++r) {
            float xv = acc[mi][ni][r] + bv;
            if (act) xv = silu_f(xv);
            Cs[(rl + q * 16 + r) * 136 + col] = (__bf16)xv;
          }
        }
      }
      __syncthreads();
#pragma unroll
      for (int rr = 0; rr < 4; ++rr) {
        int row = (tid >> 4) + rr * 16;
        int chunk = tid & 15;
        bf16x8 v = *(const bf16x8*)(Cs + row * 136 + chunk * 8);
        int grow = row0 + (row >> 5) * 64 + (2 * p + ((row >> 4) & 1)) * 16 + (row & 15);
        if (grow < M)
          *(bf16x8*)(C + (size_t)grow * ldc + cstore + chunk * 8) = v;
      }
    }
  }
}

// ---------------- MFMA GEMM v9: bf16-A, XCD-swizzled ----------------
template <typename CT>
__global__ __launch_bounds__(256, 3) void gemm_v9(const __bf16* __restrict__ A,
                                                  const __bf16* __restrict__ Bt,
                                                  const float* __restrict__ bias,
                                                  CT* __restrict__ C, int M, int nx, int ny,
                                                  int ldc, int act) {
  __shared__ __bf16 As[128 * 128];
  __bf16* Cs = As;
  const int bid = blockIdx.x;
  const int xi = bid & 7;
  const int rem = bid >> 3;
  const int y = rem % ny;
  const int x = (rem / ny) * 8 + xi;
  if (x >= nx) return;
  const int tid = threadIdx.x;
  const int lane = tid & 63;
  const int wave = tid >> 6;
  const int wm = wave >> 1, wn = wave & 1;
  const int row0 = x * 128;

#pragma unroll
  for (int i = 0; i < 8; ++i) {
    int c = tid + i * 256;
    int row = c >> 4, k8 = c & 15;
    int k8s = k8 ^ (row & 7);
    const __bf16* src = A + (size_t)(row0 + row) * 128 + k8s * 8;
    __builtin_amdgcn_global_load_lds((const __attribute__((address_space(1))) void*)src,
                                     (__attribute__((address_space(3))) void*)(As + c * 8),
                                     16, 0, 0);
  }
  __syncthreads();

  const __bf16* Bbase =
      Bt + ((size_t)(y * 128 + wn * 64 + (lane & 15)) << 7) + ((lane >> 4) << 3);
  bf16x8 b[4][4];
#pragma unroll
  for (int ks = 0; ks < 4; ++ks)
#pragma unroll
    for (int ni = 0; ni < 4; ++ni) b[ks][ni] = *(const bf16x8*)(Bbase + (ni << 11) + (ks << 5));

  f32x4 acc[4][4];
#pragma unroll
  for (int mi = 0; mi < 4; ++mi)
#pragma unroll
    for (int ni = 0; ni < 4; ++ni) acc[mi][ni] = f32x4{0.f, 0.f, 0.f, 0.f};

#pragma unroll
  for (int ks = 0; ks < 4; ++ks) {
    bf16x8 a[4];
#pragma unroll
    for (int mi = 0; mi < 4; ++mi) {
      int row = wm * 64 + mi * 16 + (lane & 15);
      int byte = (row * 256 + ks * 64 + ((lane >> 4) << 4)) ^ ((row & 7) << 4);
      a[mi] = *(const bf16x8*)((const char*)As + byte);
    }
#pragma unroll
    for (int mi = 0; mi < 4; ++mi)
#pragma unroll
      for (int ni = 0; ni < 4; ++ni)
        acc[mi][ni] =
            __builtin_amdgcn_mfma_f32_16x16x32_bf16(a[mi], b[ks][ni], acc[mi][ni], 0, 0, 0);
  }

  const int cstore = y * 128;
#pragma unroll
  for (int p = 0; p < 2; ++p) {
    __syncthreads();
    int rl = (wm << 5) | ((lane >> 4) << 2);
#pragma unroll
    for (int q = 0; q < 2; ++q) {
      int mi = 2 * p + q;
#pragma unroll
      for (int ni = 0; ni < 4; ++ni) {
        int col = wn * 64 + ni * 16 + (lane & 15);
        float bv = bias ? bias[cstore + col] : 0.f;
#pragma unroll
        for (int r = 0; r < 4; ++r) {
          float xv = acc[mi][ni][r] + bv;
          if (act) xv = silu_f(xv);
          Cs[(rl + q * 16 + r) * 136 + col] = (__bf16)xv;
        }
      }
    }
    __syncthreads();
#pragma unroll
    for (int rr = 0; rr < 4; ++rr) {
      int row = (tid >> 4) + rr * 16;
      int chunk = tid & 15;
      bf16x8 v = *(const bf16x8*)(Cs + row * 136 + chunk * 8);
      int grow = row0 + (row >> 5) * 64 + (2 * p + ((row >> 4) & 1)) * 16 + (row & 15);
      if (grow < M)
        *(bf16x8*)(C + (size_t)grow * ldc + cstore + chunk * 8) = v;
    }
  }
}

// helper: swizzled grid size
static inline int swz_grid(int nx, int ny) { return ((nx + 7) / 8) * ny * 8; }

// ---------------- message (fully p-indexed): attn + vm[p] ----------------
__global__ __launch_bounds__(256) void msg_kernel(const __bf16* __restrict__ qkv,
                                                  const __bf16* __restrict__ fm,
                                                  const float* __restrict__ r2,
                                                  const int* __restrict__ srclist,
                                                  const int* __restrict__ dstlist,
                                                  __bf16* __restrict__ vm) {
  int p = blockIdx.x * 2 + (threadIdx.x >> 7);
  int h = threadIdx.x & 127;
  int src = srclist[p], dst = dstlist[p];
  float qv = (float)qkv[(size_t)dst * 384 + h];
  float kv = (float)qkv[(size_t)src * 384 + 128 + h];
  float vv = (float)qkv[(size_t)src * 384 + 256 + h];
  float t = qv * kv * (float)fm[(size_t)p * 384 + h];
#pragma unroll
  for (int off = 8; off >= 1; off >>= 1) t += __shfl_xor(t, off, 16);
  float r = r2[p];
  float cut = 0.5f * (__cosf(0.6283185307f * r) + 1.f);
  cut = (r < 5.f) ? cut : 0.f;
  float attn = silu_f(t) * cut;
  vm[(size_t)p * H + h] = (__bf16)(vv * (float)fm[(size_t)p * 384 + 128 + h] * attn);
}

// ---------------- CSR build: histogram, scan, fill ----------------
__global__ __launch_bounds__(256) void hist_kernel(const int* __restrict__ ei,
                                                   int* __restrict__ cnt) {
  int e = blockIdx.x * 256 + threadIdx.x;
  if (e < N_EDGES) atomicAdd(&cnt[ei[N_EDGES + e]], 1);
}

__global__ __launch_bounds__(1024) void scan_kernel(const int* __restrict__ cnt,
                                                    int* __restrict__ rowptr) {
  __shared__ int wsum[16];
  int t = threadIdx.x;
  int base = t * 10;
  int local[10];
  int s = 0;
#pragma unroll
  for (int i = 0; i < 10; ++i) {
    int v = (base + i < N_NODES) ? cnt[base + i] : 0;
    local[i] = s;
    s += v;
  }
  int lane = t & 63, wave = t >> 6;
  int inc = s;
#pragma unroll
  for (int off = 1; off < 64; off <<= 1) {
    int u = __shfl_up(inc, off, 64);
    if (lane >= off) inc += u;
  }
  if (lane == 63) wsum[wave] = inc;
  __syncthreads();
  if (t == 0) {
    int acc = 0;
#pragma unroll
    for (int w = 0; w < 16; ++w) { int v = wsum[w]; wsum[w] = acc; acc += v; }
  }
  __syncthreads();
  int excl = inc - s + wsum[wave];
#pragma unroll
  for (int i = 0; i < 10; ++i)
    if (base + i <= N_NODES) rowptr[base + i] = excl + local[i];
}

__global__ __launch_bounds__(256) void fill_kernel(const int* __restrict__ ei,
                                                   const int* __restrict__ rowptr,
                                                   int* __restrict__ cursor,
                                                   int* __restrict__ elist,
                                                   int* __restrict__ srclist,
                                                   int* __restrict__ dstlist) {
  int e = blockIdx.x * 256 + threadIdx.x;
  if (e < N_EDGES) {
    int s = ei[e];
    int d = ei[N_EDGES + e];
    int p = atomicAdd(&cursor[d], 1);
    int idx = rowptr[d] + p;
    elist[idx] = e;
    srclist[idx] = s;
    dstlist[idx] = d;
  }
}

// ---------------- node kernel: gather + edge update; ONE node per 128-thread block ----------
__global__ __launch_bounds__(128) void node_kernel(const __bf16* __restrict__ vm,
                                                   const __bf16* __restrict__ s,
                                                   const __bf16* __restrict__ vecwT,
                                                   const __bf16* __restrict__ vtT,
                                                   const __bf16* __restrict__ vsT,
                                                   const __bf16* __restrict__ fm,
                                                   const float* __restrict__ d2,
                                                   const int* __restrict__ srclist,
                                                   const int* __restrict__ elist,
                                                   const int* __restrict__ rowptr,
                                                   __bf16* __restrict__ x_agg,
                                                   __bf16* __restrict__ avb,
                                                   float* __restrict__ df) {
  int n = blockIdx.x;
  int h = threadIdx.x;  // 0..127
  int beg = rowptr[n], end = rowptr[n + 1];

  bf16x8 vt8 = *(const bf16x8*)(vtT + (size_t)n * 1024 + h * 8);
  float vt[L];
#pragma unroll
  for (int l = 0; l < L; l++) vt[l] = (float)vt8[l];

  float ax = 0.f;
  float av[L] = {};
  for (int p = beg; p < end; ++p) {
    int src = srclist[p];
    const float* dd = d2 + (size_t)p * L;
    float d[L], sd2 = 0.f;
#pragma unroll
    for (int l = 0; l < L; l++) {
      d[l] = dd[l];
      sd2 += d[l] * d[l];
    }
    ax += (float)vm[(size_t)p * H + h];
    float s1 = (float)s[(size_t)p * 256 + h];
    float s2 = (float)s[(size_t)p * 256 + 128 + h];
    bf16x8 vw8 = *(const bf16x8*)(vecwT + (size_t)src * 1024 + h * 8);
    bf16x8 vs8 = *(const bf16x8*)(vsT + (size_t)src * 1024 + h * 8);
    float dot = 0.f, p1 = 0.f, p2 = 0.f;
#pragma unroll
    for (int l = 0; l < L; l++) {
      av[l] += (float)vw8[l] * s1 + s2 * d[l];
      float bb = (float)vs8[l];
      dot += vt[l] * bb;
      p1 += vt[l] * d[l];
      p2 += bb * d[l];
    }
    float wdot = dot - p1 * p2 * (2.f - sd2);
    df[(size_t)elist[p] * H + h] = (float)fm[(size_t)p * 384 + 256 + h] * wdot;
  }
  x_agg[(size_t)n * H + h] = (__bf16)ax;
  bf16x8 pack;
#pragma unroll
  for (int l = 0; l < L; l++) pack[l] = (__bf16)av[l];
  *(bf16x8*)(avb + (size_t)n * 1024 + h * 8) = pack;
}

// ---------------- final: dx = vdot*o2+o3 ; dvec = avb + vec3*o1 (write-only) ----------------
__global__ __launch_bounds__(256) void final_kernel(const __bf16* __restrict__ o,
                                                    const float* __restrict__ vdot,
                                                    const __bf16* __restrict__ vec3,
                                                    const __bf16* __restrict__ avb,
                                                    float* __restrict__ dx,
                                                    float* __restrict__ dvec, int n_nodes) {
  int n = blockIdx.x * 2 + (threadIdx.x >> 7);
  int h = threadIdx.x & 127;
  if (n >= n_nodes) return;
  float o1 = (float)o[(size_t)n * 384 + h];
  float o2 = (float)o[(size_t)n * 384 + 128 + h];
  float o3 = (float)o[(size_t)n * 384 + 256 + h];
  dx[(size_t)n * H + h] = vdot[(size_t)n * H + h] * o2 + o3;
  bf16x8 av8 = *(const bf16x8*)(avb + (size_t)n * 1024 + h * 8);
  float* drow = dvec + (size_t)n * L * H + h;
  const __bf16* v3 = vec3 + (size_t)n * 1024 + h;
#pragma unroll
  for (int l = 0; l < L; l++) drow[l * H] = (float)av8[l] + (float)v3[l * 128] * o1;
}

extern "C" void kernel_launch(void* const* d_in, const int* in_sizes, int n_in, void* d_out,
                              int out_size, void* d_ws, size_t ws_size, hipStream_t stream) {
  const float* x = (const float*)d_in[0];
  const float* vec = (const float*)d_in[1];
  const float* f_ij = (const float*)d_in[2];
  const float* d_ij = (const float*)d_in[3];
  const float* r_ij = (const float*)d_in[4];
  const int* ei = (const int*)d_in[5];
  const float* ln_g = (const float*)d_in[6];
  const float* ln_b = (const float*)d_in[7];
  const float* vln_w = (const float*)d_in[8];
  const float* W_vec = (const float*)d_in[9];
  const float* W_q = (const float*)d_in[10];
  const float* b_q = (const float*)d_in[11];
  const float* W_k = (const float*)d_in[12];
  const float* b_k = (const float*)d_in[13];
  const float* W_v = (const float*)d_in[14];
  const float* b_v = (const float*)d_in[15];
  const float* W_dk = (const float*)d_in[16];
  const float* b_dk = (const float*)d_in[17];
  const float* W_dv = (const float*)d_in[18];
  const float* b_dv = (const float*)d_in[19];
  const float* W_s = (const float*)d_in[20];
  const float* b_s = (const float*)d_in[21];
  const float* W_f = (const float*)d_in[22];
  const float* b_f = (const float*)d_in[23];
  const float* W_src = (const float*)d_in[24];
  const float* W_trg = (const float*)d_in[25];
  const float* W_o = (const float*)d_in[26];
  const float* b_o = (const float*)d_in[27];

  float* out = (float*)d_out;
  float* dx = out;
  float* dvec = out + (size_t)N_NODES * H;
  float* df = dvec + (size_t)N_NODES * L * H;

  // ---- workspace plan (offsets in f32 slots; ~268 MB) ----
  float* ws = (float*)d_ws;
  __bf16* vecw = (__bf16*)ws;                 // NL*128 bf16
  __bf16* vec3 = (__bf16*)(ws + 5120000);     // NL*128 bf16
  __bf16* vtT = (__bf16*)(ws + 10240000);     // N*1024 bf16 [n][h][8]
  __bf16* vsT = (__bf16*)(ws + 15360000);     // N*1024 bf16
  __bf16* fm = (__bf16*)(ws + 20480000);      // E*384 bf16 (p-order)
  __bf16* vm = (__bf16*)(ws + 32768000);      // E*128 bf16 (p-order)
  __bf16* s_buf = (__bf16*)(ws + 36864000);   // E*256 bf16 (p-order)
  __bf16* qkv = (__bf16*)(ws + 45056000);     // N*384 bf16 (region reused as o_buf bf16)
  __bf16* xln = (__bf16*)(ws + 48896000);     // N*128 bf16 (+tail slack)
  __bf16* xagg = (__bf16*)(ws + 49536000);    // N*128 bf16 (+tail slack)
  float* vdot = ws + 50176000;                // N*128 f32
  __bf16* Wt = (__bf16*)(ws + 51456000);      // [2048][128] bf16
  float* bqkv = ws + 51456000 + 131072;       // 384
  float* bfm = bqkv + 384;                    // 384
  int* rowptr = (int*)(bfm + 384);            // 10,001
  int* elist = rowptr + 10001;                // 64,000
  int* srclist = elist + 64000;               // 64,000
  int* dstlist = srclist + 64000;             // 64,000
  int* cnt = dstlist + 64000;                 // 10,000
  int* cursor = cnt + 10000;                  // 10,000 (adjacent: single memset)
  __bf16* fijb = (__bf16*)(ws + 51900000);    // E*128 bf16 (p-order)
  __bf16* vecwT = (__bf16*)(ws + 56000000);   // N*1024 bf16 [n][h][8]
  float* d2 = ws + 61200000;                  // E*8 f32 (p-order)
  float* r2 = ws + 61712000;                  // E f32 (p-order)
  __bf16* avb = (__bf16*)(ws + 61776000);     // N*1024 bf16 [n][h][8]

  __bf16* o_buf = qkv;  // overwrites qkv after it's consumed (msg)

  dim3 b256(256);

  // CSR build (depends only on ei)
  hipMemsetAsync(cnt, 0, 2 * N_NODES * sizeof(int), stream);
  hist_kernel<<<dim3((N_EDGES + 255) / 256), b256, 0, stream>>>(ei, cnt);
  scan_kernel<<<dim3(1), dim3(1024), 0, stream>>>(cnt, rowptr);
  fill_kernel<<<dim3((N_EDGES + 255) / 256), b256, 0, stream>>>(ei, rowptr, cursor, elist,
                                                                srclist, dstlist);
  // prep2: wconv + biases + vecw/vecwT + ln + fgather + dgather (one launch, after fill)
  prep2_kernel<<<dim3(17758), b256, 0, stream>>>(
      W_vec, W_q, W_k, W_v, W_dk, W_dv, W_s, W_trg, W_src, W_f, W_o, b_q, b_k, b_v, b_dk,
      b_dv, b_f, Wt, bqkv, bfm, x, ln_g, ln_b, xln, vec, vln_w, vecw, vecwT, f_ij, d_ij,
      r_ij, elist, fijb, d2, r2);

  // vdot (dedicated, no-spill kernel; Wt rows 0..255 = vec1|vec2)
  vdot_gemm<<<dim3(625), b256, 0, stream>>>(vecw, Wt, vdot);

  // mega GEMM: big (vec3|vtT|vsT) + qkv + fm in one launch
  gemm_multi<<<dim3(1896 + 240 + 1512), b256, 0, stream>>>(vecw, xln, fijb, Wt, bqkv, bfm,
                                                           vec3, vtT, vsT, qkv, fm);

  // message -> vm[p] (fully p-indexed)
  msg_kernel<<<dim3(N_EDGES / 2), b256, 0, stream>>>(qkv, fm, r2, srclist, dstlist, vm);
  // s = silu(vm @ W_s + b) (p-order)
  gemm_v9<__bf16><<<dim3(swz_grid(500, 2)), b256, 0, stream>>>(
      vm, Wt + (size_t)1408 * 128, b_s, s_buf, N_EDGES, 500, 2, 256, 1);
  // node-major: one node per 128-thread block; av -> bf16 avb
  node_kernel<<<dim3(N_NODES), dim3(128), 0, stream>>>(vm, s_buf, vecwT, vtT, vsT, fm, d2,
                                                       srclist, elist, rowptr, xagg, avb, df);
  // o = xagg @ W_o + b (bf16 out; overwrites qkv region: consumed in msg)
  gemm_v9<__bf16><<<dim3(swz_grid(79, 3)), b256, 0, stream>>>(
      xagg, Wt + (size_t)1664 * 128, b_o, o_buf, N_NODES, 79, 3, 384, 0);
  // final: dx = vdot*o2+o3 ; dvec = avb + vec3*o1 (write-only)
  final_kernel<<<dim3(5000), b256, 0, stream>>>(o_buf, vdot, vec3, avb, dx, dvec, N_NODES);
}